// Round 3
// baseline (471.356 us; speedup 1.0000x reference)
//
#include <hip/hip_runtime.h>
#include <cstdint>
#include <cstddef>

#define T_STEPS 50
#define B_SZ    1024
#define N_INP   784
#define H_SZ    256
#define L_SZ    10
#define M_TOT   (T_STEPS * B_SZ)   // 51200
#define NK0     26                 // K padded to 26*32 = 832
#define NSLICE  5                  // 5 balanced base-256 digits of rint(Wi*2^40): exact (|Wi|<0.5)

typedef int v4i  __attribute__((ext_vector_type(4)));
typedef int v16i __attribute__((ext_vector_type(16)));

// ---------------------------------------------------------------------------
// Phase 0a: transpose Wr[h][k] (256x256, fp32) -> WrTz[k][h]; block (0,0) also
// zeroes dummy row 256 (global gather pad target).
// ---------------------------------------------------------------------------
__global__ __launch_bounds__(256) void transpose_wr(const float* __restrict__ Wr,
                                                    float* __restrict__ WrTz) {
    __shared__ float tile[32][33];
    int bx = blockIdx.x * 32, by = blockIdx.y * 32;
    int tx = threadIdx.x % 32, ty = threadIdx.x / 32;   // 32 x 8
    #pragma unroll
    for (int j = 0; j < 32; j += 8)
        tile[ty + j][tx] = Wr[(size_t)(by + ty + j) * H_SZ + bx + tx];
    if (blockIdx.x == 0 && blockIdx.y == 0)
        WrTz[(size_t)256 * H_SZ + threadIdx.x] = 0.0f;   // dummy zero row
    __syncthreads();
    #pragma unroll
    for (int j = 0; j < 32; j += 8)
        WrTz[(size_t)(bx + ty + j) * H_SZ + by + tx] = tile[tx][ty + j];
}

// ---------------------------------------------------------------------------
// Phase 0b: Wi -> 5 balanced int8 digits of rint(Wi*2^40), fragment-linear.
// (R5/R6-verified exact, absmax 0.)
// ---------------------------------------------------------------------------
__global__ __launch_bounds__(128) void prep_packed(const float* __restrict__ Wi,
                                                   uint8_t* __restrict__ SBp) {
    const int nt   = blockIdx.x;
    const int k0   = blockIdx.y * 2 + (threadIdx.x >> 6);
    const int lane = threadIdx.x & 63;
    const int h    = nt * 32 + (lane & 31);
    const int g    = k0 * 2 + (lane >> 5);     // 16-float group index

    int wd[NSLICE][4] = {};
    #pragma unroll
    for (int u = 0; u < 16; ++u) {
        double wv = 0.0;
        if (g < 49) wv = (double)Wi[(size_t)h * N_INP + g * 16 + u];
        double r = rint(wv * 0x1p40);
        #pragma unroll
        for (int j = 0; j < NSLICE - 1; ++j) {
            double q  = floor((r + 128.0) * 0.00390625);
            double dj = r - 256.0 * q;                     // in [-128,127]
            wd[j][u >> 2] |= ((int)dj & 0xFF) << ((u & 3) * 8);
            r = q;
        }
        wd[NSLICE - 1][u >> 2] |= ((int)r & 0xFF) << ((u & 3) * 8);
    }
    uint8_t* base = SBp + ((size_t)(nt * NK0 + k0) * NSLICE) * 1024 + lane * 16;
    #pragma unroll
    for (int j = 0; j < NSLICE; ++j)
        *(v4i*)(base + (size_t)j * 1024) = (v4i){wd[j][0], wd[j][1], wd[j][2], wd[j][3]};
}

// ---------------------------------------------------------------------------
// Phase 0c: pack X (binary fp32) -> fragment-linear int8 (R6-verified).
// ---------------------------------------------------------------------------
__global__ __launch_bounds__(256) void pack_x(const float* __restrict__ X,
                                              uint8_t* __restrict__ Ap) {
    const int mt  = blockIdx.x;       // 1600
    const int tid = threadIdx.x;
    #pragma unroll
    for (int i = 0; i < 7; ++i) {
        int s = tid + i * 256;
        if (s < NK0 * 64) {
            int k0 = s >> 6, lane = s & 63;
            int m = mt * 32 + (lane & 31);
            int g = k0 * 2 + (lane >> 5);
            unsigned int bw[4] = {0u, 0u, 0u, 0u};
            if (g < 49) {
                const float* src = X + (size_t)m * N_INP + g * 16;
                #pragma unroll
                for (int q = 0; q < 4; ++q) {
                    float4 f = *(const float4*)(src + q * 4);
                    bw[q] = (f.x != 0.f ? 1u : 0u) | (f.y != 0.f ? 0x100u : 0u)
                          | (f.z != 0.f ? 0x10000u : 0u) | (f.w != 0.f ? 0x1000000u : 0u);
                }
            }
            *(v4i*)(Ap + ((size_t)(mt * NK0 + k0)) * 1024 + lane * 16) =
                (v4i){(int)bw[0], (int)bw[1], (int)bw[2], (int)bw[3]};
        }
    }
}

// ---------------------------------------------------------------------------
// Phase 1: cur = X @ Wi.T exactly via 5 int8-digit MFMAs. (unchanged)
// ---------------------------------------------------------------------------
__global__ __launch_bounds__(256) void gemm_i8s(const uint8_t* __restrict__ Ap,
                                                const uint8_t* __restrict__ SBp,
                                                double* __restrict__ cur) {
    __shared__ __align__(16) uint8_t Bs[2][2 * NSLICE * 1024];   // 2 x 10 KB

    const int tid   = threadIdx.x;
    const int wave  = tid >> 6;
    const int lane  = tid & 63;
    const int ghalf = lane >> 5;
    const int nt    = blockIdx.y;
    const int mt0   = (blockIdx.x * 4 + wave) * 2;     // wave owns mt0, mt0+1
    const int mt1   = mt0 + 1;

    const uint8_t* ap0 = Ap + (size_t)mt0 * NK0 * 1024 + lane * 16;
    const uint8_t* ap1 = Ap + (size_t)mt1 * NK0 * 1024 + lane * 16;
    const uint8_t* bbase = SBp + ((size_t)nt * NK0 * NSLICE) * 1024;

    {
        const uint8_t* src = bbase;
        #pragma unroll
        for (int i = 0; i < 2; ++i) {
            int s = tid + i * 256;
            *(v4i*)(Bs[0] + s * 16) = *(const v4i*)(src + s * 16);
        }
        if (tid < 128) {
            int s = tid + 512;
            *(v4i*)(Bs[0] + s * 16) = *(const v4i*)(src + s * 16);
        }
    }
    v4i a0c = *(const v4i*)(ap0);
    v4i a0n = *(const v4i*)(ap0 + 1024);
    v4i a1c = *(const v4i*)(ap1);
    v4i a1n = *(const v4i*)(ap1 + 1024);
    __syncthreads();

    v16i acc0[NSLICE] = {};
    v16i acc1[NSLICE] = {};

    for (int p = 0; p < 13; ++p) {
        const int cb = p & 1;
        v4i b0c = a0c, b0n = a0n, b1c = a1c, b1n = a1n;
        if (p < 12) {
            const uint8_t* src = bbase + (size_t)(p + 1) * 2 * NSLICE * 1024;
            uint8_t* dst = Bs[cb ^ 1];
            #pragma unroll
            for (int i = 0; i < 2; ++i) {
                int s = tid + i * 256;
                *(v4i*)(dst + s * 16) = *(const v4i*)(src + s * 16);
            }
            if (tid < 128) {
                int s = tid + 512;
                *(v4i*)(dst + s * 16) = *(const v4i*)(src + s * 16);
            }
            a0c = *(const v4i*)(ap0 + (size_t)(2 * p + 2) * 1024);
            a0n = *(const v4i*)(ap0 + (size_t)(2 * p + 3) * 1024);
            a1c = *(const v4i*)(ap1 + (size_t)(2 * p + 2) * 1024);
            a1n = *(const v4i*)(ap1 + (size_t)(2 * p + 3) * 1024);
        }
        #pragma unroll
        for (int dk = 0; dk < 2; ++dk) {
            v4i aa0 = dk ? b0n : b0c;
            v4i aa1 = dk ? b1n : b1c;
            #pragma unroll
            for (int j = 0; j < NSLICE; ++j) {
                v4i b = *(const v4i*)(Bs[cb] + (dk * NSLICE + j) * 1024 + lane * 16);
                acc0[j] = __builtin_amdgcn_mfma_i32_32x32x32_i8(aa0, b, acc0[j], 0, 0, 0);
                acc1[j] = __builtin_amdgcn_mfma_i32_32x32x32_i8(aa1, b, acc1[j], 0, 0, 0);
            }
        }
        __syncthreads();
    }

    const int h = nt * 32 + (lane & 31);
    #pragma unroll
    for (int r = 0; r < 16; ++r) {
        int mloc = (r & 3) + 8 * (r >> 2) + 4 * ghalf;
        double s0 = (double)acc0[4][r];
        s0 = s0 * 256.0 + (double)acc0[3][r];
        s0 = s0 * 256.0 + (double)acc0[2][r];
        s0 = s0 * 256.0 + (double)acc0[1][r];
        s0 = s0 * 256.0 + (double)acc0[0][r];
        cur[(size_t)(mt0 * 32 + mloc) * H_SZ + h] = s0 * 0x1p-40;
        double s1 = (double)acc1[4][r];
        s1 = s1 * 256.0 + (double)acc1[3][r];
        s1 = s1 * 256.0 + (double)acc1[2][r];
        s1 = s1 * 256.0 + (double)acc1[0 + 1][r];
        s1 = s1 * 256.0 + (double)acc1[0][r];
        cur[(size_t)(mt1 * 32 + mloc) * H_SZ + h] = s1 * 0x1p-40;
    }
}

// ---------------------------------------------------------------------------
// Phase 2 v4: 50 LIF steps fp64. Block = 1024 thr = 4 batch elems x 256 h,
// 1 block/CU, 16 waves. Hybrid gather (rows 0..127 LDS / 128..255 global)
// kept from v3, but NO block-wide barrier in the time loop: the 4 waves of
// one batch element sync among themselves via LDS tag spins (monotonic step
// tags, ping-pong mask/list slots). The 4 groups free-run, so every SIMD
// (one wave per group) always has independent work to cover spins/stalls —
// this restores the inter-block overlap v3 lost. Fences are LDS-only
// (s_waitcnt lgkmcnt(0)), so in-flight global loads are never drained.
// Protocol per step t (P=t&1, Q=P^1):
//   1 dynamics -> ballot(t)
//   2 lane0: zmS[P]=mask; lgkm-fence; tagA[P]=t+1
//   3 prefetch inp(t+1)
//   4 spin tagB[Q]>=t (lists(t-1) complete); fence
//   5 gather from listL/listG[Q]  (LDS loop 1-deep, global loop 2-deep)
//   6 spin tagA[P]>=t+1 (all 4 masks); fence; build lists[P]; fence;
//     lane0: tagB[P]=t+1
//   7 syn update
// Overwrite safety: any write of slot X at t+2 is gated by a spin that
// transitively follows the slowest wave's read of X at t (checked for
// zmS, listL/G, tagA/B in both directions). 32 pads per list make the
// 2-deep speculative prefetch garbage-free (max read idx cG+31 <= 159).
// fp64 value set and reduction order identical to v3 (absmax-0 verified);
// pads hit zeroed rows -> exact +0.0.
// ---------------------------------------------------------------------------
#define FENCE_LDS() asm volatile("s_waitcnt lgkmcnt(0)" ::: "memory")

#define SNN_STEP(T_CUR, P_, Q_, nnLp, nnGp, nnLq, nnGq)                          \
  {                                                                              \
    /* 1: dynamics, reference op order, fp64 */                                  \
    double v_dec = v + 0.05 * ((0.0 - v) + syn);                                 \
    double i_dec = 0.9 * syn;                                                    \
    bool   z_new = v_dec > 0.5;                                                  \
    v = z_new ? 0.0 : v_dec;                                                     \
    cnt += z_new ? 1 : 0;                                                        \
    unsigned long long bal = __ballot((int)z_new);                               \
    /* 2: publish mask then tagA (fence between) */                              \
    if (lane == 0) zmS[P_][bl][wvg] = bal;                                       \
    FENCE_LDS();                                                                 \
    if (lane == 0) tagA[P_][bl][wvg] = (unsigned)(T_CUR) + 1u;                   \
    /* 3: next-step input prefetch (never drained by LDS fences) */              \
    int tn = ((T_CUR) < T_STEPS - 1) ? (T_CUR) + 1 : (T_CUR);                    \
    double inp_n = curb[(size_t)tn * (B_SZ * H_SZ)];                             \
    /* 4: wait for lists(t-1) complete */                                        \
    while (tagB[Q_][bl][0] < (unsigned)(T_CUR) ||                                \
           tagB[Q_][bl][1] < (unsigned)(T_CUR) ||                                \
           tagB[Q_][bl][2] < (unsigned)(T_CUR) ||                                \
           tagB[Q_][bl][3] < (unsigned)(T_CUR)) {}                               \
    FENCE_LDS();                                                                 \
    /* 5: gather */                                                              \
    double r0 = 0.0, r1 = 0.0, r2 = 0.0, r3 = 0.0;                               \
    {                                                                            \
      const int nL = nnLp, nG = nnGp;                                            \
      const int* ll = (const int*)&listL[Q_][bl][0];                             \
      const int* lg = (const int*)&listG[Q_][bl][0];                             \
      /* issue global batches 0,1 (16 loads in flight) */                        \
      float ga0, ga1, ga2, ga3, ga4, ga5, ga6, ga7;                              \
      float gb0, gb1, gb2, gb3, gb4, gb5, gb6, gb7;                              \
      {                                                                          \
        v4i w0 = *(const v4i*)(lg);  v4i w1 = *(const v4i*)(lg + 4);             \
        ga0 = *(const float*)(wrb + ((uint32_t)w0.x + hoff));                    \
        ga1 = *(const float*)(wrb + ((uint32_t)w0.y + hoff));                    \
        ga2 = *(const float*)(wrb + ((uint32_t)w0.z + hoff));                    \
        ga3 = *(const float*)(wrb + ((uint32_t)w0.w + hoff));                    \
        ga4 = *(const float*)(wrb + ((uint32_t)w1.x + hoff));                    \
        ga5 = *(const float*)(wrb + ((uint32_t)w1.y + hoff));                    \
        ga6 = *(const float*)(wrb + ((uint32_t)w1.z + hoff));                    \
        ga7 = *(const float*)(wrb + ((uint32_t)w1.w + hoff));                    \
        v4i y0 = *(const v4i*)(lg + 8); v4i y1 = *(const v4i*)(lg + 12);         \
        gb0 = *(const float*)(wrb + ((uint32_t)y0.x + hoff));                    \
        gb1 = *(const float*)(wrb + ((uint32_t)y0.y + hoff));                    \
        gb2 = *(const float*)(wrb + ((uint32_t)y0.z + hoff));                    \
        gb3 = *(const float*)(wrb + ((uint32_t)y0.w + hoff));                    \
        gb4 = *(const float*)(wrb + ((uint32_t)y1.x + hoff));                    \
        gb5 = *(const float*)(wrb + ((uint32_t)y1.y + hoff));                    \
        gb6 = *(const float*)(wrb + ((uint32_t)y1.z + hoff));                    \
        gb7 = *(const float*)(wrb + ((uint32_t)y1.w + hoff));                    \
      }                                                                          \
      /* LDS loop, 1-deep pipelined (covers global batch-0/1 latency too) */     \
      float e0, e1, e2, e3, e4, e5, e6, e7;                                      \
      {                                                                          \
        v4i u0 = *(const v4i*)(ll); v4i u1 = *(const v4i*)(ll + 4);              \
        e0 = wrlh[u0.x]; e1 = wrlh[u0.y]; e2 = wrlh[u0.z]; e3 = wrlh[u0.w];      \
        e4 = wrlh[u1.x]; e5 = wrlh[u1.y]; e6 = wrlh[u1.z]; e7 = wrlh[u1.w];      \
      }                                                                          \
      for (int j = 0; j < nL; j += 8) {                                          \
        float p0 = e0, p1 = e1, p2 = e2, p3 = e3;                                \
        float p4 = e4, p5 = e5, p6 = e6, p7 = e7;                                \
        v4i u0 = *(const v4i*)(ll + j + 8);                                      \
        v4i u1 = *(const v4i*)(ll + j + 12);                                     \
        e0 = wrlh[u0.x]; e1 = wrlh[u0.y]; e2 = wrlh[u0.z]; e3 = wrlh[u0.w];      \
        e4 = wrlh[u1.x]; e5 = wrlh[u1.y]; e6 = wrlh[u1.z]; e7 = wrlh[u1.w];      \
        r0 += (double)p0 + (double)p1;                                           \
        r1 += (double)p2 + (double)p3;                                           \
        r2 += (double)p4 + (double)p5;                                           \
        r3 += (double)p6 + (double)p7;                                           \
      }                                                                          \
      /* global loop, 2 batches in flight */                                     \
      for (int j = 0; j < nG; j += 16) {                                         \
        float p0 = ga0, p1 = ga1, p2 = ga2, p3 = ga3;                            \
        float p4 = ga4, p5 = ga5, p6 = ga6, p7 = ga7;                            \
        {                                                                        \
          v4i w0 = *(const v4i*)(lg + j + 16);                                   \
          v4i w1 = *(const v4i*)(lg + j + 20);                                   \
          ga0 = *(const float*)(wrb + ((uint32_t)w0.x + hoff));                  \
          ga1 = *(const float*)(wrb + ((uint32_t)w0.y + hoff));                  \
          ga2 = *(const float*)(wrb + ((uint32_t)w0.z + hoff));                  \
          ga3 = *(const float*)(wrb + ((uint32_t)w0.w + hoff));                  \
          ga4 = *(const float*)(wrb + ((uint32_t)w1.x + hoff));                  \
          ga5 = *(const float*)(wrb + ((uint32_t)w1.y + hoff));                  \
          ga6 = *(const float*)(wrb + ((uint32_t)w1.z + hoff));                  \
          ga7 = *(const float*)(wrb + ((uint32_t)w1.w + hoff));                  \
        }                                                                        \
        r0 += (double)p0 + (double)p1;                                           \
        r1 += (double)p2 + (double)p3;                                           \
        r2 += (double)p4 + (double)p5;                                           \
        r3 += (double)p6 + (double)p7;                                           \
        float q0 = gb0, q1 = gb1, q2 = gb2, q3 = gb3;                            \
        float q4 = gb4, q5 = gb5, q6 = gb6, q7 = gb7;                            \
        {                                                                        \
          v4i w0 = *(const v4i*)(lg + j + 24);                                   \
          v4i w1 = *(const v4i*)(lg + j + 28);                                   \
          gb0 = *(const float*)(wrb + ((uint32_t)w0.x + hoff));                  \
          gb1 = *(const float*)(wrb + ((uint32_t)w0.y + hoff));                  \
          gb2 = *(const float*)(wrb + ((uint32_t)w0.z + hoff));                  \
          gb3 = *(const float*)(wrb + ((uint32_t)w0.w + hoff));                  \
          gb4 = *(const float*)(wrb + ((uint32_t)w1.x + hoff));                  \
          gb5 = *(const float*)(wrb + ((uint32_t)w1.y + hoff));                  \
          gb6 = *(const float*)(wrb + ((uint32_t)w1.z + hoff));                  \
          gb7 = *(const float*)(wrb + ((uint32_t)w1.w + hoff));                  \
        }                                                                        \
        r0 += (double)q0 + (double)q1;                                           \
        r1 += (double)q2 + (double)q3;                                           \
        r2 += (double)q4 + (double)q5;                                           \
        r3 += (double)q6 + (double)q7;                                           \
      }                                                                          \
    }                                                                            \
    /* 6: collect masks, build shared lists for slot P_ */                       \
    while (tagA[P_][bl][0] < (unsigned)(T_CUR) + 1u ||                           \
           tagA[P_][bl][1] < (unsigned)(T_CUR) + 1u ||                           \
           tagA[P_][bl][2] < (unsigned)(T_CUR) + 1u ||                           \
           tagA[P_][bl][3] < (unsigned)(T_CUR) + 1u) {}                          \
    FENCE_LDS();                                                                 \
    {                                                                            \
      unsigned long long m0 = zmS[P_][bl][0], m1 = zmS[P_][bl][1],               \
                         m2 = zmS[P_][bl][2], m3 = zmS[P_][bl][3];               \
      int c0 = __popcll(m0), c1 = __popcll(m1);                                  \
      int c2 = __popcll(m2), c3 = __popcll(m3);                                  \
      int cL = c0 + c1, cG = c2 + c3;                                            \
      unsigned long long word = (h < 64) ? m0 : (h < 128) ? m1                   \
                               : (h < 192) ? m2 : m3;                            \
      int bit = h & 63;                                                          \
      bool act = (word >> bit) & 1ull;                                           \
      int pos = __popcll(word & ((1ull << bit) - 1ull));                         \
      if (h < 128) {                                                             \
        if (act) listL[P_][bl][((h >> 6) ? c0 : 0) + pos] = h << 8;              \
        if (h < 32) listL[P_][bl][cL + h] = 128 << 8;      /* LDS zero row */    \
      } else {                                                                   \
        if (act) listG[P_][bl][(((h >> 6) == 3) ? c2 : 0) + pos] = h << 10;      \
        if (h < 160) listG[P_][bl][cG + (h - 128)] = 256 << 10; /* glob zero */  \
      }                                                                          \
      FENCE_LDS();                                                               \
      if (lane == 0) tagB[P_][bl][wvg] = (unsigned)(T_CUR) + 1u;                 \
      nnLq = cL; nnGq = cG;                                                      \
    }                                                                            \
    /* 7 */                                                                      \
    syn = (i_dec + inp_c) + ((r0 + r1) + (r2 + r3));                             \
    inp_c = inp_n;                                                               \
  }

__global__ __launch_bounds__(1024) void snn_scan(const double* __restrict__ cur,
                                                 const float* __restrict__ WrTz,
                                                 const float* __restrict__ Wout,
                                                 const float* __restrict__ bout,
                                                 float* __restrict__ out) {
    const int tid  = threadIdx.x;
    const int bl   = tid >> 8;          // batch element within block (0..3)
    const int h    = tid & 255;         // neuron
    const int wvg  = h >> 6;            // wave within group (0..3)
    const int lane = tid & 63;
    const int b    = blockIdx.x * 4 + bl;

    __shared__ __align__(16) float WrL[129 * 256];          // 132,096 B
    __shared__ volatile unsigned long long zmS[2][4][4];    //     256 B
    __shared__ volatile unsigned tagA[2][4][4];             //     128 B
    __shared__ volatile unsigned tagB[2][4][4];             //     128 B
    __shared__ __align__(16) int listL[2][4][160];          //   5,120 B
    __shared__ __align__(16) int listG[2][4][160];          //   5,120 B
    __shared__ float cntS[4][256];                          //   4,096 B
                                                            // 146,944 B total

    // stage WrT rows 0..127 into LDS; row 128 = zeros (LDS-list pad target)
    for (int s = tid; s < (129 * 256) / 4; s += 1024) {
        float4 val = (s < 8192) ? ((const float4*)WrTz)[s]
                                : make_float4(0.f, 0.f, 0.f, 0.f);
        ((float4*)WrL)[s] = val;
    }
    if (tid < 32) {
        int pp = tid >> 4, gg = (tid >> 2) & 3, ww = tid & 3;
        tagA[pp][gg][ww] = 0u;
        tagB[pp][gg][ww] = 0u;
        zmS[pp][gg][ww]  = 0ull;
    }
    if (h < 32) {   // step-0 gather reads pads speculatively: init both slots
        listL[0][bl][h] = 128 << 8;  listL[1][bl][h] = 128 << 8;
        listG[0][bl][h] = 256 << 10; listG[1][bl][h] = 256 << 10;
    }
    __syncthreads();   // the ONLY block-wide barrier before the epilogue

    double v = 0.0, syn = 0.0;
    int cnt = 0;
    int nnL0 = 0, nnG0 = 0, nnL1 = 0, nnG1 = 0;

    const double*  curb = cur + (size_t)b * H_SZ + h;
    const char*    wrb  = (const char*)WrTz;            // global gather base
    const float*   wrlh = WrL + h;                      // LDS gather base
    const uint32_t hoff = (uint32_t)(h * 4);
    double inp_c = curb[0];                             // t=0 input

    for (int t2 = 0; t2 < T_STEPS; t2 += 2) {
        SNN_STEP(t2,     0, 1, nnL1, nnG1, nnL0, nnG0);
        SNN_STEP(t2 + 1, 1, 0, nnL0, nnG0, nnL1, nnG1);
    }

    cntS[bl][h] = (float)cnt;
    __syncthreads();
    if (h < L_SZ) {
        double s = 0.0;
        for (int k = 0; k < H_SZ; ++k)
            s += (double)cntS[bl][k] * (double)Wout[(size_t)h * H_SZ + k];
        s += (double)T_STEPS * (double)bout[h];
        out[(size_t)b * L_SZ + h] = (float)(s / (double)T_STEPS);
    }
}

// ---------------------------------------------------------------------------
extern "C" void kernel_launch(void* const* d_in, const int* in_sizes, int n_in,
                              void* d_out, int out_size, void* d_ws, size_t ws_size,
                              hipStream_t stream) {
    const float* x    = (const float*)d_in[0];   // [50,1024,784]
    const float* Wi   = (const float*)d_in[1];   // [256,784]
    const float* Wr   = (const float*)d_in[2];   // [256,256]
    const float* Wout = (const float*)d_in[3];   // [10,256]
    const float* bout = (const float*)d_in[4];   // [10]
    float* out = (float*)d_out;                  // [1024,10]

    // ws layout (~148.8 MB)
    char* ws = (char*)d_ws;
    double*  cur  = (double*)(ws);                       // 104,857,600 B
    float*   WrTz = (float*)(ws + 104857600);            // 257 rows x 256 x 4 = 263,168 B
    uint8_t* SBp  = (uint8_t*)(ws + 105121792);          //   1,064,960 B
    uint8_t* Ap   = (uint8_t*)(ws + 106186752);          //  42,598,400 B

    hipLaunchKernelGGL(transpose_wr, dim3(8, 8), dim3(256), 0, stream, Wr, WrTz);
    hipLaunchKernelGGL(prep_packed, dim3(8, 13), dim3(128), 0, stream, Wi, SBp);
    hipLaunchKernelGGL(pack_x, dim3(M_TOT / 32), dim3(256), 0, stream, x, Ap);
    hipLaunchKernelGGL(gemm_i8s, dim3(M_TOT / 256, 8), dim3(256), 0, stream, Ap, SBp, cur);
    hipLaunchKernelGGL(snn_scan, dim3(B_SZ / 4), dim3(1024), 0, stream,
                       cur, WrTz, Wout, bout, out);
}

// Round 4
// 383.438 us; speedup vs baseline: 1.2293x; 1.2293x over previous
//
#include <hip/hip_runtime.h>
#include <cstdint>
#include <cstddef>

#define T_STEPS 50
#define B_SZ    1024
#define N_INP   784
#define H_SZ    256
#define L_SZ    10
#define M_TOT   (T_STEPS * B_SZ)   // 51200
#define NK0     26                 // K padded to 26*32 = 832
#define NSLICE  5                  // 5 balanced base-256 digits of rint(Wi*2^40): exact (|Wi|<0.5)

typedef int v4i  __attribute__((ext_vector_type(4)));
typedef int v16i __attribute__((ext_vector_type(16)));

// ---------------------------------------------------------------------------
// Phase 0a: transpose Wr[h][k] (256x256, fp32) -> WrTz[k][h]; block (0,0) also
// zeroes dummy row 256 (gather pad target).
// ---------------------------------------------------------------------------
__global__ __launch_bounds__(256) void transpose_wr(const float* __restrict__ Wr,
                                                    float* __restrict__ WrTz) {
    __shared__ float tile[32][33];
    int bx = blockIdx.x * 32, by = blockIdx.y * 32;
    int tx = threadIdx.x % 32, ty = threadIdx.x / 32;   // 32 x 8
    #pragma unroll
    for (int j = 0; j < 32; j += 8)
        tile[ty + j][tx] = Wr[(size_t)(by + ty + j) * H_SZ + bx + tx];
    if (blockIdx.x == 0 && blockIdx.y == 0)
        WrTz[(size_t)256 * H_SZ + threadIdx.x] = 0.0f;   // dummy zero row
    __syncthreads();
    #pragma unroll
    for (int j = 0; j < 32; j += 8)
        WrTz[(size_t)(bx + ty + j) * H_SZ + by + tx] = tile[tx][ty + j];
}

// ---------------------------------------------------------------------------
// Phase 0b: Wi -> 5 balanced int8 digits of rint(Wi*2^40), fragment-linear.
// (R5/R6-verified exact, absmax 0.)
// ---------------------------------------------------------------------------
__global__ __launch_bounds__(128) void prep_packed(const float* __restrict__ Wi,
                                                   uint8_t* __restrict__ SBp) {
    const int nt   = blockIdx.x;
    const int k0   = blockIdx.y * 2 + (threadIdx.x >> 6);
    const int lane = threadIdx.x & 63;
    const int h    = nt * 32 + (lane & 31);
    const int g    = k0 * 2 + (lane >> 5);     // 16-float group index

    int wd[NSLICE][4] = {};
    #pragma unroll
    for (int u = 0; u < 16; ++u) {
        double wv = 0.0;
        if (g < 49) wv = (double)Wi[(size_t)h * N_INP + g * 16 + u];
        double r = rint(wv * 0x1p40);
        #pragma unroll
        for (int j = 0; j < NSLICE - 1; ++j) {
            double q  = floor((r + 128.0) * 0.00390625);
            double dj = r - 256.0 * q;                     // in [-128,127]
            wd[j][u >> 2] |= ((int)dj & 0xFF) << ((u & 3) * 8);
            r = q;
        }
        wd[NSLICE - 1][u >> 2] |= ((int)r & 0xFF) << ((u & 3) * 8);
    }
    uint8_t* base = SBp + ((size_t)(nt * NK0 + k0) * NSLICE) * 1024 + lane * 16;
    #pragma unroll
    for (int j = 0; j < NSLICE; ++j)
        *(v4i*)(base + (size_t)j * 1024) = (v4i){wd[j][0], wd[j][1], wd[j][2], wd[j][3]};
}

// ---------------------------------------------------------------------------
// Phase 0c: pack X (binary fp32) -> fragment-linear int8 (R6-verified).
// ---------------------------------------------------------------------------
__global__ __launch_bounds__(256) void pack_x(const float* __restrict__ X,
                                              uint8_t* __restrict__ Ap) {
    const int mt  = blockIdx.x;       // 1600
    const int tid = threadIdx.x;
    #pragma unroll
    for (int i = 0; i < 7; ++i) {
        int s = tid + i * 256;
        if (s < NK0 * 64) {
            int k0 = s >> 6, lane = s & 63;
            int m = mt * 32 + (lane & 31);
            int g = k0 * 2 + (lane >> 5);
            unsigned int bw[4] = {0u, 0u, 0u, 0u};
            if (g < 49) {
                const float* src = X + (size_t)m * N_INP + g * 16;
                #pragma unroll
                for (int q = 0; q < 4; ++q) {
                    float4 f = *(const float4*)(src + q * 4);
                    bw[q] = (f.x != 0.f ? 1u : 0u) | (f.y != 0.f ? 0x100u : 0u)
                          | (f.z != 0.f ? 0x10000u : 0u) | (f.w != 0.f ? 0x1000000u : 0u);
                }
            }
            *(v4i*)(Ap + ((size_t)(mt * NK0 + k0)) * 1024 + lane * 16) =
                (v4i){(int)bw[0], (int)bw[1], (int)bw[2], (int)bw[3]};
        }
    }
}

// ---------------------------------------------------------------------------
// Phase 1 v2: cur = X @ Wi.T exactly via 5 int8-digit MFMAs.
// Changes vs v1 (values bit-identical: same ascending-k0 integer accumulation):
//  - B staged via __builtin_amdgcn_global_load_lds width=16 (no VALU/register
//    roundtrip; loads stay in flight under the MFMAs until the barrier).
//  - Stage = 4 k0-steps (20 KB/buffer, 2 x 20 KB LDS): 40 MFMAs per barrier
//    instead of 20; 7 barrier drains instead of 13.
//  - A fragments prefetched one stage ahead (8 x v4i regs).
// Tail: stage 6 holds k0 24..25 (12 KB staged incl. 2 KB never-read pad; the
// pad's global source spills into the adjacent Ap region -> valid memory).
// ---------------------------------------------------------------------------
typedef __attribute__((address_space(1))) uint32_t glds_g;
typedef __attribute__((address_space(3))) uint32_t glds_l;

#define STAGE_B(dstbuf, srcp, NI)                                               \
    {                                                                           \
        _Pragma("unroll")                                                       \
        for (int j_ = 0; j_ < (NI); ++j_) {                                     \
            int s_ = j_ * 256 + tid;                                            \
            __builtin_amdgcn_global_load_lds(                                   \
                (glds_g*)((srcp) + (size_t)s_ * 16),                            \
                (glds_l*)((dstbuf) + (size_t)s_ * 16), 16, 0, 0);               \
        }                                                                       \
    }

#define MFMA_STAGE(CB, A0, A1, NK)                                              \
    _Pragma("unroll")                                                           \
    for (int dk = 0; dk < (NK); ++dk) {                                         \
        _Pragma("unroll")                                                       \
        for (int j = 0; j < NSLICE; ++j) {                                      \
            v4i b = *(const v4i*)(Bs[CB] + (dk * NSLICE + j) * 1024 + lane * 16); \
            acc0[j] = __builtin_amdgcn_mfma_i32_32x32x32_i8(A0[dk], b, acc0[j], 0, 0, 0); \
            acc1[j] = __builtin_amdgcn_mfma_i32_32x32x32_i8(A1[dk], b, acc1[j], 0, 0, 0); \
        }                                                                       \
    }

__global__ __launch_bounds__(256) void gemm_i8s(const uint8_t* __restrict__ Ap,
                                                const uint8_t* __restrict__ SBp,
                                                double* __restrict__ cur) {
    __shared__ __align__(16) uint8_t Bs[2][4 * NSLICE * 1024];   // 2 x 20 KB

    const int tid   = threadIdx.x;
    const int wave  = tid >> 6;
    const int lane  = tid & 63;
    const int ghalf = lane >> 5;
    const int nt    = blockIdx.y;
    const int mt0   = (blockIdx.x * 4 + wave) * 2;     // wave owns mt0, mt0+1
    const int mt1   = mt0 + 1;

    const uint8_t* ap0 = Ap + (size_t)mt0 * NK0 * 1024 + lane * 16;
    const uint8_t* ap1 = Ap + (size_t)mt1 * NK0 * 1024 + lane * 16;
    const uint8_t* bbase = SBp + ((size_t)nt * NK0 * NSLICE) * 1024;

    v4i a0[4], a1[4], n0[4], n1[4];

    // prologue: stage stage-0 (k0 0..3), prefetch its A fragments
    STAGE_B(Bs[0], bbase, 5);
    #pragma unroll
    for (int dk = 0; dk < 4; ++dk) {
        a0[dk] = *(const v4i*)(ap0 + (size_t)dk * 1024);
        a1[dk] = *(const v4i*)(ap1 + (size_t)dk * 1024);
    }
    __syncthreads();                       // vmcnt(0): stage-0 resident

    v16i acc0[NSLICE] = {};
    v16i acc1[NSLICE] = {};

    for (int s = 0; s < 6; ++s) {
        const int cb = s & 1;
        if (s < 5) {                       // full next stage: 4 k0, 20 KB
            STAGE_B(Bs[cb ^ 1], bbase + (size_t)(s + 1) * 20480, 5);
            #pragma unroll
            for (int dk = 0; dk < 4; ++dk) {
                n0[dk] = *(const v4i*)(ap0 + (size_t)((s + 1) * 4 + dk) * 1024);
                n1[dk] = *(const v4i*)(ap1 + (size_t)((s + 1) * 4 + dk) * 1024);
            }
        } else {                           // tail stage: k0 24..25 (+pad)
            STAGE_B(Bs[cb ^ 1], bbase + (size_t)6 * 20480, 3);
            #pragma unroll
            for (int dk = 0; dk < 2; ++dk) {
                n0[dk] = *(const v4i*)(ap0 + (size_t)(24 + dk) * 1024);
                n1[dk] = *(const v4i*)(ap1 + (size_t)(24 + dk) * 1024);
            }
        }
        MFMA_STAGE(cb, a0, a1, 4);
        __syncthreads();                   // next stage resident; cb free to reuse
        #pragma unroll
        for (int dk = 0; dk < 4; ++dk) { a0[dk] = n0[dk]; a1[dk] = n1[dk]; }
    }
    MFMA_STAGE(0, a0, a1, 2);              // tail: k0 24..25 in Bs[0]

    // recombine digits (exact integer Horner in fp64) and store both m-tiles
    const int h = nt * 32 + (lane & 31);
    #pragma unroll
    for (int r = 0; r < 16; ++r) {
        int mloc = (r & 3) + 8 * (r >> 2) + 4 * ghalf;
        double s0 = (double)acc0[4][r];
        s0 = s0 * 256.0 + (double)acc0[3][r];
        s0 = s0 * 256.0 + (double)acc0[2][r];
        s0 = s0 * 256.0 + (double)acc0[1][r];
        s0 = s0 * 256.0 + (double)acc0[0][r];
        cur[(size_t)(mt0 * 32 + mloc) * H_SZ + h] = s0 * 0x1p-40;
        double s1 = (double)acc1[4][r];
        s1 = s1 * 256.0 + (double)acc1[3][r];
        s1 = s1 * 256.0 + (double)acc1[2][r];
        s1 = s1 * 256.0 + (double)acc1[1][r];
        s1 = s1 * 256.0 + (double)acc1[0][r];
        cur[(size_t)(mt1 * 32 + mloc) * H_SZ + h] = s1 * 0x1p-40;
    }
}

// ---------------------------------------------------------------------------
// Phase 2 (v2, reverted verbatim — best measured scan, ~88 µs):
// 50 LIF steps fp64, block = batch (256 thr = 4 waves). ONE barrier per step:
// ballot masks ping-pong (zmS[2][4]); after the barrier each wave builds a
// PRIVATE padded spike list for the next step in its own LDS slice. List
// entries pre-scaled to row byte offsets; 8 entries read as 2x ds_read_b128.
// ---------------------------------------------------------------------------
__global__ __launch_bounds__(256) void snn_scan(const double* __restrict__ cur,
                                                const float* __restrict__ WrTz,
                                                const float* __restrict__ Wout,
                                                const float* __restrict__ bout,
                                                float* __restrict__ out) {
    const int b    = blockIdx.x;
    const int h    = threadIdx.x;
    const int wv   = h >> 6;
    const int lane = h & 63;

    __shared__ unsigned long long zmS[2][4];
    __shared__ __align__(16) int listS[2][4][264];   // [parity][wave][entry], h<<10
    __shared__ float cntS[H_SZ];

    double v = 0.0, syn = 0.0;
    int cnt = 0;
    int nn[2] = {0, 0};

    const double* curb = cur + (size_t)b * H_SZ + h;
    const char*   wrb  = (const char*)WrTz;          // SGPR-uniform base
    const uint32_t hoff = (uint32_t)(h * 4);
    double inp_c = curb[0];                          // prefetch t=0

    for (int t = 0; t < T_STEPS; ++t) {
        const int p = t & 1;
        const int q = p ^ 1;
        // prefetch next step's input drive (full step of slack)
        int tn = (t < T_STEPS - 1) ? t + 1 : t;
        double inp_n = curb[(size_t)tn * B_SZ * H_SZ];

        // LIF dynamics, reference op order, fp64
        double v_dec = v + 0.05 * ((0.0 - v) + syn);
        double i_dec = 0.9 * syn;
        bool   z_new = v_dec > 0.5;
        v = z_new ? 0.0 : v_dec;
        cnt += z_new ? 1 : 0;

        // gather recurrent drive from this wave's private list (built last step)
        double r0 = 0.0, r1 = 0.0, r2 = 0.0, r3 = 0.0;
        const int* lp = listS[p][wv];
        const int  n  = nn[p];
        for (int j = 0; j < n; j += 8) {
            v4i w0 = *(const v4i*)(lp + j);
            v4i w1 = *(const v4i*)(lp + j + 4);
            float f0 = *(const float*)(wrb + ((uint32_t)w0.x + hoff));
            float f1 = *(const float*)(wrb + ((uint32_t)w0.y + hoff));
            float f2 = *(const float*)(wrb + ((uint32_t)w0.z + hoff));
            float f3 = *(const float*)(wrb + ((uint32_t)w0.w + hoff));
            float f4 = *(const float*)(wrb + ((uint32_t)w1.x + hoff));
            float f5 = *(const float*)(wrb + ((uint32_t)w1.y + hoff));
            float f6 = *(const float*)(wrb + ((uint32_t)w1.z + hoff));
            float f7 = *(const float*)(wrb + ((uint32_t)w1.w + hoff));
            r0 += (double)f0 + (double)f1;
            r1 += (double)f2 + (double)f3;
            r2 += (double)f4 + (double)f5;
            r3 += (double)f6 + (double)f7;
        }

        // publish new spike mask (ping-pong slot q)
        unsigned long long bal = __ballot((int)z_new);
        if (lane == 0) zmS[q][wv] = bal;
        __syncthreads();                             // the ONLY barrier per step

        // build this wave's private next-step list (ascending h, pre-scaled, padded)
        {
            unsigned long long m0 = zmS[q][0], m1 = zmS[q][1],
                               m2 = zmS[q][2], m3 = zmS[q][3];
            int c0 = __popcll(m0), c1 = __popcll(m1),
                c2 = __popcll(m2), c3 = __popcll(m3);
            const int wi = lane >> 4;                // word holding h=4*lane..4*lane+3
            unsigned long long word = zmS[q][wi];
            int basew = (wi > 0 ? c0 : 0) + (wi > 1 ? c1 : 0) + (wi > 2 ? c2 : 0);
            int* lw = listS[q][wv];
            const int hb = 4 * lane;
            #pragma unroll
            for (int u = 0; u < 4; ++u) {
                int bit = (hb + u) & 63;
                bool act = (word >> bit) & 1ull;
                int  pos = __popcll(word & ((1ull << bit) - 1ull));
                if (act) lw[basew + pos] = (hb + u) << 10;
            }
            int tot = c0 + c1 + c2 + c3;
            if (lane < 8) lw[tot + lane] = 256 << 10;   // pad -> zero row of WrTz
            nn[q] = tot;
        }

        syn = (i_dec + inp_c) + ((r0 + r1) + (r2 + r3));
        inp_c = inp_n;
        // no second barrier: private lists are same-wave in-order; zmS slot
        // reuse is separated by the next step's barrier.
    }

    cntS[h] = (float)cnt;
    __syncthreads();
    if (h < L_SZ) {
        double s = 0.0;
        for (int k = 0; k < H_SZ; ++k)
            s += (double)cntS[k] * (double)Wout[(size_t)h * H_SZ + k];
        s += (double)T_STEPS * (double)bout[h];
        out[(size_t)b * L_SZ + h] = (float)(s / (double)T_STEPS);
    }
}

// ---------------------------------------------------------------------------
extern "C" void kernel_launch(void* const* d_in, const int* in_sizes, int n_in,
                              void* d_out, int out_size, void* d_ws, size_t ws_size,
                              hipStream_t stream) {
    const float* x    = (const float*)d_in[0];   // [50,1024,784]
    const float* Wi   = (const float*)d_in[1];   // [256,784]
    const float* Wr   = (const float*)d_in[2];   // [256,256]
    const float* Wout = (const float*)d_in[3];   // [10,256]
    const float* bout = (const float*)d_in[4];   // [10]
    float* out = (float*)d_out;                  // [1024,10]

    // ws layout (~148.8 MB)
    char* ws = (char*)d_ws;
    double*  cur  = (double*)(ws);                       // 104,857,600 B
    float*   WrTz = (float*)(ws + 104857600);            // 257 rows x 256 x 4 = 263,168 B
    uint8_t* SBp  = (uint8_t*)(ws + 105121792);          //   1,064,960 B
    uint8_t* Ap   = (uint8_t*)(ws + 106186752);          //  42,598,400 B

    hipLaunchKernelGGL(transpose_wr, dim3(8, 8), dim3(256), 0, stream, Wr, WrTz);
    hipLaunchKernelGGL(prep_packed, dim3(8, 13), dim3(128), 0, stream, Wi, SBp);
    hipLaunchKernelGGL(pack_x, dim3(M_TOT / 32), dim3(256), 0, stream, x, Ap);
    hipLaunchKernelGGL(gemm_i8s, dim3(M_TOT / 256, 8), dim3(256), 0, stream, Ap, SBp, cur);
    hipLaunchKernelGGL(snn_scan, dim3(B_SZ), dim3(256), 0, stream,
                       cur, WrTz, Wout, bout, out);
}